// Round 3
// baseline (395.778 us; speedup 1.0000x reference)
//
#include <hip/hip_runtime.h>
#include <hip/hip_bf16.h>

#define HH    64
#define WW    96
#define MD    40
#define KD    81
#define HW    (HH*WW)          /* 6144 */
#define CHW   (128*HW)
#define SCALE 0.08838834764831845f   /* 1/sqrt(128) */
#define LSTR  72               /* ushorts per staged LDS row (64 bf16 + pad, 16B-aligned) */
#define GSTR  100              /* dwords per sGd row: diag writes stride -99≡29 mod 32 */

typedef __attribute__((ext_vector_type(8))) short bf16x8;
typedef __attribute__((ext_vector_type(4))) float f32x4;

__device__ inline unsigned pk2(float lo, float hi) {
    __hip_bfloat162 h = __float22bfloat162_rn(make_float2(lo, hi));   // v_cvt_pk_bf16_f32
    return *reinterpret_cast<unsigned*>(&h);
}

// One workgroup per (dy, y, b); 256 threads = 4 waves.
// G[x2][x] = sum_c x1[c][x]*x2[c][x2] via mfma_f32_16x16x32_bf16 (2x2 wave grid,
// 3x3 tiles each); acc scattered pre-shifted into sGd[dx][x]; epilogue is a
// mask-free b128 LDS->global copy.
__global__ __launch_bounds__(256, 5) void corr_kernel(
    const float* __restrict__ x1, const float* __restrict__ x2,
    float* __restrict__ out)
{
    const int dy  = blockIdx.x;
    const int y   = blockIdx.y;
    const int b   = blockIdx.z;
    const int tid = threadIdx.x;

    float* outbase = out + ((size_t)b * (KD * KD) + (size_t)dy * KD) * HW
                         + (size_t)y * WW;

    const int y2 = y + dy - MD;
    if (y2 < 0 || y2 >= HH) {
        const float4 z = make_float4(0.f, 0.f, 0.f, 0.f);
        for (int f = tid; f < KD * (WW / 4); f += 256) {
            const int dx = f / (WW / 4);
            const int x4 = (f - dx * (WW / 4)) * 4;
            *reinterpret_cast<float4*>(outbase + (size_t)dx * HW + x4) = z;
        }
        return;
    }

    // Union LDS: staging (2 x 96 x 72 ushorts = 27648 B) then sGd (81x100 fp32
    // = 32400 B). Block LDS = 32400 B -> 5 blocks/CU.
    __shared__ __align__(16) char smem[KD * GSTR * 4];
    unsigned short* sA = reinterpret_cast<unsigned short*>(smem);   // x1 row [x][c]
    unsigned short* sB = sA + WW * LSTR;                            // x2 row [x2][c]
    float*          sGd = reinterpret_cast<float*>(smem);           // out-slab [dx][x]

    const float* x1p = x1 + (size_t)b * CHW + (size_t)y  * WW;
    const float* x2p = x2 + (size_t)b * CHW + (size_t)y2 * WW;

    const int lane = tid & 63;
    const int wave = tid >> 6;
    const int m0   = (wave >> 1) * 48;   // x2-tile base
    const int n0   = (wave & 1) * 48;    // x-tile base
    const int lr   = lane & 15;
    const int q    = lane >> 4;

    f32x4 acc[3][3];
    #pragma unroll
    for (int i = 0; i < 3; ++i)
        #pragma unroll
        for (int j = 0; j < 3; ++j)
            acc[i][j] = (f32x4){0.f, 0.f, 0.f, 0.f};

    for (int h = 0; h < 2; ++h) {
        if (h) __syncthreads();          // protect prev-half fragment reads
        const float* g1 = x1p + (size_t)h * 64 * HW;
        const float* g2 = x2p + (size_t)h * 64 * HW;
        // stage 64 channels of both rows as bf16 [x][c]; 384 jobs of (x-pair, 8ch)
        for (int j = tid; j < 384; j += 256) {
            const int xp = (j % 48) * 2;
            const int cg = (j / 48) * 8;
            {
                const float* p1 = g1 + (size_t)cg * HW + xp;
                float2 u[8];
                #pragma unroll
                for (int c = 0; c < 8; ++c) u[c] = *reinterpret_cast<const float2*>(p1 + (size_t)c * HW);
                uint4 w0, w1;
                w0.x = pk2(u[0].x, u[1].x); w0.y = pk2(u[2].x, u[3].x);
                w0.z = pk2(u[4].x, u[5].x); w0.w = pk2(u[6].x, u[7].x);
                w1.x = pk2(u[0].y, u[1].y); w1.y = pk2(u[2].y, u[3].y);
                w1.z = pk2(u[4].y, u[5].y); w1.w = pk2(u[6].y, u[7].y);
                *reinterpret_cast<uint4*>(&sA[(xp    ) * LSTR + cg]) = w0;
                *reinterpret_cast<uint4*>(&sA[(xp + 1) * LSTR + cg]) = w1;
            }
            {
                const float* p2 = g2 + (size_t)cg * HW + xp;
                float2 u[8];
                #pragma unroll
                for (int c = 0; c < 8; ++c) u[c] = *reinterpret_cast<const float2*>(p2 + (size_t)c * HW);
                uint4 w0, w1;
                w0.x = pk2(u[0].x, u[1].x); w0.y = pk2(u[2].x, u[3].x);
                w0.z = pk2(u[4].x, u[5].x); w0.w = pk2(u[6].x, u[7].x);
                w1.x = pk2(u[0].y, u[1].y); w1.y = pk2(u[2].y, u[3].y);
                w1.z = pk2(u[4].y, u[5].y); w1.w = pk2(u[6].y, u[7].y);
                *reinterpret_cast<uint4*>(&sB[(xp    ) * LSTR + cg]) = w0;
                *reinterpret_cast<uint4*>(&sB[(xp + 1) * LSTR + cg]) = w1;
            }
        }
        __syncthreads();

        #pragma unroll
        for (int kk = 0; kk < 2; ++kk) {
            const int cl = kk * 32 + q * 8;
            bf16x8 af[3], bg[3];
            #pragma unroll
            for (int i = 0; i < 3; ++i)
                af[i] = *reinterpret_cast<const bf16x8*>(&sB[(m0 + 16 * i + lr) * LSTR + cl]);
            #pragma unroll
            for (int j = 0; j < 3; ++j)
                bg[j] = *reinterpret_cast<const bf16x8*>(&sA[(n0 + 16 * j + lr) * LSTR + cl]);
            #pragma unroll
            for (int i = 0; i < 3; ++i)
                #pragma unroll
                for (int j = 0; j < 3; ++j)
                    acc[i][j] = __builtin_amdgcn_mfma_f32_16x16x32_bf16(
                        af[i], bg[j], acc[i][j], 0, 0, 0);
        }
    }

    __syncthreads();                     // all fragment reads done; smem -> sGd
    {   // zero sGd (8100 dwords = 2025 float4)
        const float4 z = make_float4(0.f, 0.f, 0.f, 0.f);
        for (int j = tid; j < (KD * GSTR) / 4; j += 256)
            *reinterpret_cast<float4*>(sGd + j * 4) = z;
    }
    __syncthreads();
    // scatter acc pre-shifted: sGd[dx][x], dx = x2 - x + 40 (skip out-of-range)
    #pragma unroll
    for (int i = 0; i < 3; ++i) {
        #pragma unroll
        for (int j = 0; j < 3; ++j) {
            const int x   = n0 + 16 * j + lr;      // D col = x
            const int x2b = m0 + 16 * i + q * 4;   // D row base = x2
            #pragma unroll
            for (int r = 0; r < 4; ++r) {
                const int dx = x2b + r - x + MD;
                if (dx >= 0 && dx < KD)
                    sGd[dx * GSTR + x] = acc[i][j][r] * SCALE;
            }
        }
    }
    __syncthreads();

    // epilogue: mask-free contiguous copy, 81 rows x 24 float4
    for (int j = tid; j < KD * (WW / 4); j += 256) {   // 7.6 iters
        const int dx = j / (WW / 4);
        const int x4 = (j - dx * (WW / 4)) * 4;
        const float4 v = *reinterpret_cast<const float4*>(sGd + dx * GSTR + x4);
        *reinterpret_cast<float4*>(outbase + (size_t)dx * HW + x4) = v;
    }
}

extern "C" void kernel_launch(void* const* d_in, const int* in_sizes, int n_in,
                              void* d_out, int out_size, void* d_ws, size_t ws_size,
                              hipStream_t stream) {
    const float* x1 = (const float*)d_in[0];
    const float* x2 = (const float*)d_in[1];
    float* out = (float*)d_out;
    dim3 g(KD, HH, 2);   // dy, y, b  (dy fastest: consecutive blocks reuse x1 row in L2)
    hipLaunchKernelGGL(corr_kernel, g, dim3(256), 0, stream, x1, x2, out);
}